// Round 18
// baseline (94.789 us; speedup 1.0000x reference)
//
#include <hip/hip_runtime.h>

// LiftSplatShot voxel pooling: segment-sum of per-point features into a
// (B=2, C=64, 512, 512) fp32 grid.
//
// NUMERICS (FROZEN — r5): jitted-XLA semantics
//   q = RN32( RN32(f + 51.2f) * 5.0f ) (x/y; recip(0.2f) folds to exactly 5.0f)
//   qz = RN32( RN32(f + 5.0f) * 0.125f ); trunc; kept: px,py in [0,512), pz==0.
//
// PERF history: r8-r16 stuck at ~200us accum = LDS-atomic rate wall
// (ds_add_f32 ~0.7 lane-ops/cyc/CU). r17 removed all atomics via voxel
// OWNERSHIP (wave w owns voxels s in [16w,16w+16); plain 32-wide LDS RMW):
// 232 -> 90us total. r18: schedule tightening —
//   - double-buffered stage -> ONE barrier per chunk (was two)
//   - gather loads issued TWO chunks ahead (regA/B/C rotation, static names)
//   - safety: overwriting stage[buf] in iter k+2 requires passing bar(k+1),
//     impossible while any wave still reads stage[buf] in OWN(k).

#define NX0 512
#define NX1 512
#define CDIM 64
#define TSPAT 64             // 1(px) x 64(py) voxels per tile
#define NTILE 8192           // 2 * 512 * 8
#define CAP 256
#define LSTRIDE 65           // acc[s*65+c]: 2-way banks on all access shapes
#define SSTRIDE 68           // stage row stride (16B-aligned rows)
#define CHUNK 16
#define CNT_PAD 16

typedef float v4f __attribute__((ext_vector_type(4)));

__device__ __forceinline__ bool voxel_of(float fx, float fy, float fz,
                                         int& px, int& py) {
    float qx = (fx + 51.2f) * 5.0f;
    float qy = (fy + 51.2f) * 5.0f;
    float qz = (fz + 5.0f) * 0.125f;
    px = (int)qx; py = (int)qy;
    int pz = (int)qz;
    return (px >= 0 && px < NX0 && py >= 0 && py < NX1 && pz == 0);
}

// A: bin points into fixed-capacity per-tile lists
__global__ __launch_bounds__(256) void lss_bin(
    const float* __restrict__ points, unsigned* __restrict__ plist,
    int* __restrict__ cnt, int npoints, int per_batch)
{
    int i = blockIdx.x * 256 + threadIdx.x;
    if (i >= npoints) return;
    float fx = points[(size_t)i * 3 + 0];
    float fy = points[(size_t)i * 3 + 1];
    float fz = points[(size_t)i * 3 + 2];
    int px, py;
    if (!voxel_of(fx, fy, fz, px, py)) return;
    int b = (i >= per_batch) ? 1 : 0;
    unsigned tid = ((unsigned)b << 12) | ((unsigned)px << 3) | ((unsigned)py >> 6);
    unsigned s = (unsigned)(py & 63);
    int slot = atomicAdd(&cnt[tid * CNT_PAD], 1);
    if (slot < CAP) plist[(size_t)tid * CAP + slot] = ((unsigned)i << 6) | s;
}

// D: atomic-free ownership accumulate; 2-ahead pipeline, 1 barrier/chunk
__global__ __launch_bounds__(256, 6) void lss_accum(
    const unsigned* __restrict__ plist, const int* __restrict__ cnt,
    const float* __restrict__ x, float* __restrict__ out)
{
    __shared__ float acc[TSPAT * LSTRIDE];        // 16.6 KB
    __shared__ float stage[2 * CHUNK * SSTRIDE];  // 8.7 KB
    __shared__ int   schunk[2 * CHUNK];
    __shared__ unsigned ent[CAP];                 // 1 KB
    int tile = blockIdx.x;
    int t = threadIdx.x;

    int n = cnt[tile * CNT_PAD];
    if (n > CAP) n = CAP;

    {   // zero acc: 4160 floats = 1040 v4f
        v4f z = (v4f)(0.0f);
        v4f* a4 = (v4f*)acc;
        #pragma unroll
        for (int j = 0; j < 5; ++j) { int i = t + j * 256; if (i < 1040) a4[i] = z; }
    }
    const unsigned* pl = plist + (size_t)tile * CAP;
    if (t < n) ent[t] = pl[t];
    __syncthreads();

    int lane = t & 63, w = t >> 6;
    int pg = lane >> 4, cg = lane & 15;
    int slot = w * 4 + pg;          // 16-lane group's stage slot (0..15)
    int coff = cg * 4;

    // prologue: chunks 0 and 1 in flight
    v4f vA = (v4f)(0.0f), vB = (v4f)(0.0f);
    int sA = 0, sB = 0; bool aA = false, aB = false;
    {
        int p = slot; aA = p < n;
        if (aA) { unsigned e = ent[p]; sA = (int)(e & 63u);
                  vA = *(const v4f*)(x + ((size_t)(e >> 6)) * CDIM + coff); }
    }
    {
        int p = CHUNK + slot; aB = p < n;
        if (aB) { unsigned e = ent[p]; sB = (int)(e & 63u);
                  vB = *(const v4f*)(x + ((size_t)(e >> 6)) * CDIM + coff); }
    }

    int buf = 0;
    for (int base = 0; base < n; base += CHUNK, buf ^= 1) {
        int m = n - base; if (m > CHUNK) m = CHUNK;
        int soff = buf * CHUNK;

        // publish current chunk (regA) to stage[buf]
        if (aA) {
            *(v4f*)(stage + (soff + slot) * SSTRIDE + coff) = vA;
            if (cg == 0) schunk[soff + slot] = sA;
        }
        __syncthreads();

        // issue loads for chunk base+2*CHUNK (2 ahead; in flight during OWN)
        v4f vC = (v4f)(0.0f); int sC = 0; bool aC = false;
        {
            int p = base + 2 * CHUNK + slot; aC = p < n;
            if (aC) { unsigned e = ent[p]; sC = (int)(e & 63u);
                      vC = *(const v4f*)(x + ((size_t)(e >> 6)) * CDIM + coff); }
        }

        // OWN: wave w exclusively owns voxels s in [16w,16w+16) — no atomics
        for (int j = 0; j < m; ++j) {
            int s = schunk[soff + j];            // broadcast LDS read
            if ((s >> 4) == w) {                 // wave-uniform branch
                acc[s * LSTRIDE + lane] += stage[(soff + j) * SSTRIDE + lane];
            }
        }

        vA = vB; sA = sB; aA = aB;
        vB = vC; sB = sC; aB = aC;
    }
    __syncthreads();

    // epilogue: channel row = 64 consecutive floats = 256B per 16-lane group
    int b   = tile >> 12;
    int px  = (tile >> 3) & 511;
    int py0 = (tile & 7) << 6;
    int l16 = lane & 15, grp = lane >> 4;
    #pragma unroll
    for (int j = 0; j < 4; ++j) {
        int cc = j * 16 + w * 4 + grp;
        int sb = l16 * 4;
        v4f o;
        o.x = acc[(sb + 0) * LSTRIDE + cc];
        o.y = acc[(sb + 1) * LSTRIDE + cc];
        o.z = acc[(sb + 2) * LSTRIDE + cc];
        o.w = acc[(sb + 3) * LSTRIDE + cc];
        size_t oidx = (((size_t)(b * CDIM + cc)) << 18)
                    + ((size_t)px << 9) + (size_t)(py0 + sb);
        *(v4f*)(out + oidx) = o;
    }
}

// Fallback (r5): direct atomics into out(b,c,s) if ws too small
__global__ __launch_bounds__(256) void lss_scatter_direct(
    const float* __restrict__ points, const float* __restrict__ x,
    float* __restrict__ out, int npoints, int per_batch)
{
    long long gid = (long long)blockIdx.x * blockDim.x + threadIdx.x;
    int wave = (int)(gid >> 6);
    int lane = (int)(gid & 63);
    if (wave >= npoints) return;
    float fx = points[(size_t)wave * 3 + 0];
    float fy = points[(size_t)wave * 3 + 1];
    float fz = points[(size_t)wave * 3 + 2];
    int px, py;
    if (!voxel_of(fx, fy, fz, px, py)) return;
    int b = (wave >= per_batch) ? 1 : 0;
    float v = x[(size_t)wave * CDIM + lane];
    size_t oidx = (((size_t)(b * CDIM + lane)) << 18) + ((size_t)px << 9) + (size_t)py;
    atomicAdd(out + oidx, v);
}

extern "C" void kernel_launch(void* const* d_in, const int* in_sizes, int n_in,
                              void* d_out, int out_size, void* d_ws, size_t ws_size,
                              hipStream_t stream) {
    const float* points = (const float*)d_in[0];
    const float* x      = (const float*)d_in[1];
    float* out = (float*)d_out;

    int npoints   = in_sizes[0] / 3;   // 826560
    int per_batch = npoints / 2;       // B = 2

    const size_t WS_NEED = (size_t)NTILE * CNT_PAD * 4 + (size_t)NTILE * CAP * 4;

    if (ws_size >= WS_NEED) {
        int*      cnt   = (int*)d_ws;
        unsigned* plist = (unsigned*)(cnt + NTILE * CNT_PAD);

        (void)hipMemsetAsync(cnt, 0, (size_t)NTILE * CNT_PAD * sizeof(int), stream);
        int pblocks = (npoints + 255) / 256;
        lss_bin  <<<pblocks, 256, 0, stream>>>(points, plist, cnt, npoints, per_batch);
        lss_accum<<<NTILE, 256, 0, stream>>>(plist, cnt, x, out);
    } else {
        (void)hipMemsetAsync(d_out, 0, (size_t)out_size * sizeof(float), stream);
        long long total_threads = (long long)npoints * 64;
        int blocks = (int)((total_threads + 255) / 256);
        lss_scatter_direct<<<blocks, 256, 0, stream>>>(points, x, out, npoints, per_batch);
    }
}

// Round 19
// 91.346 us; speedup vs baseline: 1.0377x; 1.0377x over previous
//
#include <hip/hip_runtime.h>

// LiftSplatShot voxel pooling: segment-sum of per-point features into a
// (B=2, C=64, 512, 512) fp32 grid.
//
// NUMERICS (FROZEN — r5): jitted-XLA semantics
//   q = RN32( RN32(f + 51.2f) * 5.0f ) (x/y; recip(0.2f) folds to exactly 5.0f)
//   qz = RN32( RN32(f + 5.0f) * 0.125f ); trunc; kept: px,py in [0,512), pz==0.
//
// FINAL STRUCTURE (= r17, proven 90.3us; r18's deeper pipeline regressed to
// 94.8 via occupancy loss 7->6 blocks/CU — reverted):
//   bin:   per-tile fixed-cap lists (tile = 1px x 64py), ~13us
//   accum: atomic-free voxel-OWNERSHIP accumulate — chunk of 16 points
//          staged to LDS, wave w exclusively owns voxels s in [16w,16w+16),
//          plain 32-wide LDS read+add+write (no ds_add serialization, which
//          was the r8-r16 ~200us wall at ~0.7 lane-ops/cyc/CU), next chunk's
//          1KB/instr gathers issued before the OWN phase. ~74us.
//   epilogue: channel row = 64 consecutive floats = 256B per 16-lane group.
// History: 1664 (r5 direct atomics) -> 243 (r6 staged) -> 232 (r11) ->
//          90.3 (r17 ownership). 18.5x total.

#define NX0 512
#define NX1 512
#define CDIM 64
#define TSPAT 64             // 1(px) x 64(py) voxels per tile
#define NTILE 8192           // 2 * 512 * 8
#define CAP 256
#define LSTRIDE 65           // acc[s*65+c]: 2-way banks on all access shapes
#define SSTRIDE 68           // stage row stride (16B-aligned rows)
#define CHUNK 16
#define CNT_PAD 16

typedef float v4f __attribute__((ext_vector_type(4)));

__device__ __forceinline__ bool voxel_of(float fx, float fy, float fz,
                                         int& px, int& py) {
    float qx = (fx + 51.2f) * 5.0f;
    float qy = (fy + 51.2f) * 5.0f;
    float qz = (fz + 5.0f) * 0.125f;
    px = (int)qx; py = (int)qy;
    int pz = (int)qz;
    return (px >= 0 && px < NX0 && py >= 0 && py < NX1 && pz == 0);
}

// A: bin points into fixed-capacity per-tile lists
__global__ __launch_bounds__(256) void lss_bin(
    const float* __restrict__ points, unsigned* __restrict__ plist,
    int* __restrict__ cnt, int npoints, int per_batch)
{
    int i = blockIdx.x * 256 + threadIdx.x;
    if (i >= npoints) return;
    float fx = points[(size_t)i * 3 + 0];
    float fy = points[(size_t)i * 3 + 1];
    float fz = points[(size_t)i * 3 + 2];
    int px, py;
    if (!voxel_of(fx, fy, fz, px, py)) return;
    int b = (i >= per_batch) ? 1 : 0;
    unsigned tid = ((unsigned)b << 12) | ((unsigned)px << 3) | ((unsigned)py >> 6);
    unsigned s = (unsigned)(py & 63);
    int slot = atomicAdd(&cnt[tid * CNT_PAD], 1);
    if (slot < CAP) plist[(size_t)tid * CAP + slot] = ((unsigned)i << 6) | s;
}

// D: atomic-free accumulate via voxel-ownership partitioning (r17)
__global__ __launch_bounds__(256, 7) void lss_accum(
    const unsigned* __restrict__ plist, const int* __restrict__ cnt,
    const float* __restrict__ x, float* __restrict__ out)
{
    __shared__ float acc[TSPAT * LSTRIDE];      // 16.6 KB
    __shared__ float stage[CHUNK * SSTRIDE];    // 4.35 KB
    __shared__ int   schunk[CHUNK];
    __shared__ unsigned ent[CAP];               // 1 KB
    int tile = blockIdx.x;
    int t = threadIdx.x;

    int n = cnt[tile * CNT_PAD];
    if (n > CAP) n = CAP;

    {   // zero acc: 4160 floats = 1040 v4f
        v4f z = (v4f)(0.0f);
        v4f* a4 = (v4f*)acc;
        #pragma unroll
        for (int j = 0; j < 5; ++j) { int i = t + j * 256; if (i < 1040) a4[i] = z; }
    }
    const unsigned* pl = plist + (size_t)tile * CAP;
    if (t < n) ent[t] = pl[t];
    __syncthreads();

    int lane = t & 63, w = t >> 6;
    int pg = lane >> 4, cg = lane & 15;
    int slot = w * 4 + pg;          // this 16-lane group's stage slot (0..15)
    int coff = cg * 4;

    // prologue: load chunk 0 into regs
    v4f rv = (v4f)(0.0f); int rs = 0; bool ra = false;
    {
        int p = slot;
        ra = p < n;
        if (ra) {
            unsigned e = ent[p];
            rs = (int)(e & 63u);
            rv = *(const v4f*)(x + ((size_t)(e >> 6)) * CDIM + coff);
        }
    }

    for (int base = 0; base < n; base += CHUNK) {
        int m = n - base; if (m > CHUNK) m = CHUNK;

        // write current chunk regs -> stage
        if (ra) {
            *(v4f*)(stage + slot * SSTRIDE + coff) = rv;
            if (cg == 0) schunk[slot] = rs;
        }
        __syncthreads();

        // issue NEXT chunk's loads now (in flight during OWN phase)
        v4f rv2 = (v4f)(0.0f); int rs2 = 0; bool ra2 = false;
        {
            int p = base + CHUNK + slot;
            ra2 = p < n;
            if (ra2) {
                unsigned e = ent[p];
                rs2 = (int)(e & 63u);
                rv2 = *(const v4f*)(x + ((size_t)(e >> 6)) * CDIM + coff);
            }
        }

        // OWN: wave w exclusively owns voxels s in [16w, 16w+16) — no atomics
        for (int j = 0; j < m; ++j) {
            int s = schunk[j];                   // broadcast LDS read
            if ((s >> 4) == w) {                 // wave-uniform branch
                acc[s * LSTRIDE + lane] += stage[j * SSTRIDE + lane];
            }
        }
        __syncthreads();

        rv = rv2; rs = rs2; ra = ra2;
    }

    // epilogue: channel row = 64 consecutive floats = 256B per 16-lane group
    int b   = tile >> 12;
    int px  = (tile >> 3) & 511;
    int py0 = (tile & 7) << 6;
    int l16 = lane & 15, grp = lane >> 4;
    #pragma unroll
    for (int j = 0; j < 4; ++j) {
        int cc = j * 16 + w * 4 + grp;
        int sb = l16 * 4;
        v4f o;
        o.x = acc[(sb + 0) * LSTRIDE + cc];
        o.y = acc[(sb + 1) * LSTRIDE + cc];
        o.z = acc[(sb + 2) * LSTRIDE + cc];
        o.w = acc[(sb + 3) * LSTRIDE + cc];
        size_t oidx = (((size_t)(b * CDIM + cc)) << 18)
                    + ((size_t)px << 9) + (size_t)(py0 + sb);
        *(v4f*)(out + oidx) = o;
    }
}

// Fallback (r5): direct atomics into out(b,c,s) if ws too small
__global__ __launch_bounds__(256) void lss_scatter_direct(
    const float* __restrict__ points, const float* __restrict__ x,
    float* __restrict__ out, int npoints, int per_batch)
{
    long long gid = (long long)blockIdx.x * blockDim.x + threadIdx.x;
    int wave = (int)(gid >> 6);
    int lane = (int)(gid & 63);
    if (wave >= npoints) return;
    float fx = points[(size_t)wave * 3 + 0];
    float fy = points[(size_t)wave * 3 + 1];
    float fz = points[(size_t)wave * 3 + 2];
    int px, py;
    if (!voxel_of(fx, fy, fz, px, py)) return;
    int b = (wave >= per_batch) ? 1 : 0;
    float v = x[(size_t)wave * CDIM + lane];
    size_t oidx = (((size_t)(b * CDIM + lane)) << 18) + ((size_t)px << 9) + (size_t)py;
    atomicAdd(out + oidx, v);
}

extern "C" void kernel_launch(void* const* d_in, const int* in_sizes, int n_in,
                              void* d_out, int out_size, void* d_ws, size_t ws_size,
                              hipStream_t stream) {
    const float* points = (const float*)d_in[0];
    const float* x      = (const float*)d_in[1];
    float* out = (float*)d_out;

    int npoints   = in_sizes[0] / 3;   // 826560
    int per_batch = npoints / 2;       // B = 2

    const size_t WS_NEED = (size_t)NTILE * CNT_PAD * 4 + (size_t)NTILE * CAP * 4;

    if (ws_size >= WS_NEED) {
        int*      cnt   = (int*)d_ws;
        unsigned* plist = (unsigned*)(cnt + NTILE * CNT_PAD);

        (void)hipMemsetAsync(cnt, 0, (size_t)NTILE * CNT_PAD * sizeof(int), stream);
        int pblocks = (npoints + 255) / 256;
        lss_bin  <<<pblocks, 256, 0, stream>>>(points, plist, cnt, npoints, per_batch);
        lss_accum<<<NTILE, 256, 0, stream>>>(plist, cnt, x, out);
    } else {
        (void)hipMemsetAsync(d_out, 0, (size_t)out_size * sizeof(float), stream);
        long long total_threads = (long long)npoints * 64;
        int blocks = (int)((total_threads + 255) / 256);
        lss_scatter_direct<<<blocks, 256, 0, stream>>>(points, x, out, npoints, per_batch);
    }
}